// Round 18
// baseline (201.184 us; speedup 1.0000x reference)
//
#include <hip/hip_runtime.h>
#include <hip/hip_bf16.h>

typedef unsigned short u16;
typedef unsigned int u32;
typedef __attribute__((ext_vector_type(8))) short bf16x8;
typedef __attribute__((ext_vector_type(4))) float f32x4;
typedef __attribute__((ext_vector_type(16))) float f32x16;
typedef __attribute__((ext_vector_type(4))) unsigned short u16x4;

#define S_LEN 2048
#define HIDDEN 2048
#define NHEAD 16
#define QLORA 1536
#define KVLORA 512
#define NOPE_D 128
#define ROPE_D 64
#define V_D 128
#define HEAD_D 192
#define NCOMB 2176   // QLORA + KVLORA + ROPE_D + 64 pad (N=17*128)
#define LOG2E 1.442695041f

// SOFTMAX_SCALE = 192^-0.5 * mscale^2, mscale = 0.1*ln(40)+1
__device__ __constant__ float SM_SCALE_C = (float)(0.07216878364870323 *
    ((0.1 * 3.6888794541139363 + 1.0) * (0.1 * 3.6888794541139363 + 1.0)));

__device__ inline u16 f2bf(float f) {
    __hip_bfloat16 h = __float2bfloat16(f);
    return *reinterpret_cast<u16*>(&h);
}
__device__ inline u32 pack2bf(float lo, float hi) {
    float2 v = make_float2(lo, hi);
    __hip_bfloat162 h2 = __float22bfloat162_rn(v); // v_cvt_pk_bf16_f32
    return *reinterpret_cast<u32*>(&h2);
}
__device__ inline float bf2f(u16 b) {
    union { unsigned int u; float f; } v; v.u = ((unsigned int)b) << 16;
    return v.f;
}
__device__ inline void gload_lds16(const u16* g, u16* l) {
    __builtin_amdgcn_global_load_lds(
        (const __attribute__((address_space(1))) void*)g,
        (__attribute__((address_space(3))) void*)l, 16, 0, 0);
}

// bijective XCD swizzle (m204)
__device__ __forceinline__ int xcd_swizzle(int orig, int nwg) {
    int qq = nwg >> 3, rr = nwg & 7, xcd = orig & 7, loc = orig >> 3;
    return (xcd < rr) ? (xcd * (qq + 1) + loc)
                      : (rr * (qq + 1) + (xcd - rr) * qq + loc);
}

// ---------------- weight prep: hs cvt + all 5 dequants, no LDS, one launch ----------
__global__ __launch_bounds__(256)
void prep_weights(const float* __restrict__ hs,
                  const float* __restrict__ wq_a, const float* __restrict__ sq_a,
                  const float* __restrict__ wq_b, const float* __restrict__ sq_b,
                  const float* __restrict__ wkv_a, const float* __restrict__ skv_a,
                  const float* __restrict__ wkv_b, const float* __restrict__ skv_b,
                  const float* __restrict__ wo, const float* __restrict__ so,
                  u16* __restrict__ hs_bf, u16* __restrict__ wcomb,
                  u16* __restrict__ wqb_bf, u16* __restrict__ wkvb_bf,
                  u16* __restrict__ wo_bf) {
    int r = blockIdx.x * 4 + (threadIdx.x >> 6);
    const float* W; const float* Sc; u16* out; int n, K, sc_cols;
    if (r < 2048)       { W = hs;    Sc = 0;      out = hs_bf;   n = r;        K = 2048; sc_cols = 0; }
    else if (r < 3584)  { W = wq_a;  Sc = sq_a;   out = wcomb;   n = r - 2048; K = 2048; sc_cols = 16; }
    else if (r < 4160)  { W = wkv_a; Sc = skv_a;  out = wcomb + (size_t)QLORA * 2048; n = r - 3584; K = 2048; sc_cols = 16; }
    else if (r < 7232)  { W = wq_b;  Sc = sq_b;   out = wqb_bf;  n = r - 4160; K = 1536; sc_cols = 12; }
    else if (r < 11328) { W = wkv_b; Sc = skv_b;  out = wkvb_bf; n = r - 7232; K = 512;  sc_cols = 4; }
    else                { W = wo;    Sc = so;     out = wo_bf;   n = r - 11328; K = 2048; sc_cols = 16; }
    for (int k = (threadIdx.x & 63) * 8; k < K; k += 512) {
        float sc = Sc ? Sc[(n >> 7) * sc_cols + (k >> 7)] : 1.0f;
        f32x4 v0 = *(const f32x4*)(W + (size_t)n * K + k);
        f32x4 v1 = *(const f32x4*)(W + (size_t)n * K + k + 4);
        u32 w[4];
        w[0] = pack2bf(v0[0] * sc, v0[1] * sc);
        w[1] = pack2bf(v0[2] * sc, v0[3] * sc);
        w[2] = pack2bf(v1[0] * sc, v1[1] * sc);
        w[3] = pack2bf(v1[2] * sc, v1[3] * sc);
        *(__attribute__((ext_vector_type(4))) u32*)(out + (size_t)n * K + k) =
            *( __attribute__((ext_vector_type(4))) u32*)w;
    }
}

// ---------------- GEMM core v4: BK=64 dbuf + counted vmcnt (T4), raw s_barrier -------
__device__ __forceinline__ void gemm_core(
    const u16* __restrict__ A, const u16* __restrict__ W, u16* __restrict__ C,
    int M, int N, int Ktot, int Ksub, int bm, int bn, int bz,
    u16 (*As)[128 * 64], u16 (*Ws)[128 * 64]) {
    const int tid = threadIdx.x;
    const int lane = tid & 63;
    const int wv = tid >> 6;
    const int wm = wv >> 1, wn = wv & 1;
    const int lr = lane & 15, lk = lane >> 4;
    const int srow = lane >> 3;
    const int schunk = lane & 7;

    f32x4 acc[4][4] = {};

    const int kbeg = bz * Ksub;
    const int nst = Ksub >> 6;

    auto stage = [&](int buf, int k0) {
        #pragma unroll
        for (int i = 0; i < 4; ++i) {
            int t = (wv * 4 + i) * 8 + srow;
            int cs = (schunk ^ (t & 7)) << 3;
            gload_lds16(A + (size_t)(bm + t) * Ktot + k0 + cs, &As[buf][(wv * 4 + i) * 512]);
            gload_lds16(W + (size_t)(bn + t) * Ktot + k0 + cs, &Ws[buf][(wv * 4 + i) * 512]);
        }
    };

    stage(0, kbeg);
    int cur = 0;
    for (int t = 0; t < nst; ++t) {
        if (t + 1 < nst) {
            stage(cur ^ 1, kbeg + (t + 1) * 64);            // 8 loads in flight across barriers
            asm volatile("s_waitcnt vmcnt(8)" ::: "memory"); // drain ONLY stage(cur)
        } else {
            asm volatile("s_waitcnt vmcnt(0)" ::: "memory");
        }
        __builtin_amdgcn_sched_barrier(0);                   // rule #18: pin reads below
        __builtin_amdgcn_s_barrier();                        // all waves' stage(cur) landed
        #pragma unroll
        for (int kh = 0; kh < 2; ++kh) {
            bf16x8 af[4], bfr[4];
            #pragma unroll
            for (int mi = 0; mi < 4; ++mi) {
                int r = wm * 64 + mi * 16 + lr;
                af[mi] = *(const bf16x8*)&As[cur][r * 64 + (((kh * 4 + lk) ^ (lr & 7)) << 3)];
            }
            #pragma unroll
            for (int ni = 0; ni < 4; ++ni) {
                int r = wn * 64 + ni * 16 + lr;
                bfr[ni] = *(const bf16x8*)&Ws[cur][r * 64 + (((kh * 4 + lk) ^ (lr & 7)) << 3)];
            }
            __builtin_amdgcn_s_setprio(1);
            #pragma unroll
            for (int mi = 0; mi < 4; ++mi)
                #pragma unroll
                for (int ni = 0; ni < 4; ++ni)
                    acc[mi][ni] = __builtin_amdgcn_mfma_f32_16x16x32_bf16(af[mi], bfr[ni], acc[mi][ni], 0, 0, 0);
            __builtin_amdgcn_s_setprio(0);
        }
        __builtin_amdgcn_s_barrier();                        // all reads of cur done before overwrite
        cur ^= 1;
    }

    u16* Pb = C + (size_t)bz * M * N;
    #pragma unroll
    for (int mi = 0; mi < 4; ++mi)
        #pragma unroll
        for (int ni = 0; ni < 4; ++ni)
            #pragma unroll
            for (int j = 0; j < 4; ++j) {
                int r = bm + wm * 64 + mi * 16 + lk * 4 + j;
                int c = bn + wn * 64 + ni * 16 + lr;
                if (c < N) Pb[(size_t)r * N + c] = f2bf(acc[mi][ni][j]);
            }
}

// ---------------- generic split-K GEMM (bf16 partial slices) ----------------
__global__ __launch_bounds__(256)
void gemm_bf16(const u16* __restrict__ A, const u16* __restrict__ W,
               u16* __restrict__ C, int M, int N, int Ktot, int Ksub) {
    __shared__ u16 As[2][128 * 64];
    __shared__ u16 Ws[2][128 * 64];
    const int gx = gridDim.x, gy = gridDim.y;
    const int nwg = gx * gy * gridDim.z;
    const int orig = blockIdx.x + gx * (blockIdx.y + gy * blockIdx.z);
    const int wg = xcd_swizzle(orig, nwg);
    const int bn = (wg % gx) * 128;
    const int bm = ((wg / gx) % gy) * 128;
    const int bz = wg / (gx * gy);
    gemm_core(A, W, C, M, N, Ktot, Ksub, bm, bn, bz, As, Ws);
}

// ---------------- merged qh (z=1, direct bf16) + kvb GEMM ----------------
// qh blocks [0,384): 24 K-steps each (scheduled first); kvb blocks [384,896): 8 K-steps.
__global__ __launch_bounds__(256)
void gemm_qh_kvb(const u16* __restrict__ lqn, const u16* __restrict__ wqb, u16* __restrict__ qh,
                 const u16* __restrict__ kvn, const u16* __restrict__ wkvb, u16* __restrict__ kvb) {
    __shared__ u16 As[2][128 * 64];
    __shared__ u16 Ws[2][128 * 64];
    const int NWG = 24 * 16 + 32 * 16;   // 896
    const int wg = xcd_swizzle(blockIdx.x, NWG);
    if (wg < 24 * 16) {
        const int bn = (wg % 24) * 128;
        const int bm = (wg / 24) * 128;
        gemm_core(lqn, wqb, qh, S_LEN, NHEAD * HEAD_D, QLORA, QLORA, bm, bn, 0, As, Ws);
    } else {
        const int w2 = wg - 24 * 16;
        const int bn = (w2 % 32) * 128;
        const int bm = (w2 / 32) * 128;
        gemm_core(kvn, wkvb, kvb, S_LEN, NHEAD * 256, KVLORA, 512, bm, bn, 0, As, Ws);
    }
}

// ---------------- fused split-K(2) bf16-partial reduce + dual rmsnorm ----------------
__global__ __launch_bounds__(256)
void reduce_rms_comb(const u16* __restrict__ P,
                     const float* __restrict__ q_ln, const float* __restrict__ kv_ln,
                     u16* __restrict__ lqn, u16* __restrict__ kvn, u16* __restrict__ kpe) {
    __shared__ float vbuf[NCOMB];
    __shared__ float r2[2][4];
    const int row = blockIdx.x;
    const u16* p0 = P + (size_t)row * NCOMB;
    const size_t st = (size_t)S_LEN * NCOMB;
    float ssq = 0.f, ssk = 0.f;
    for (int c = threadIdx.x * 8; c < NCOMB; c += 2048) {
        bf16x8 a0 = *(const bf16x8*)(p0 + c);
        bf16x8 a1 = *(const bf16x8*)(p0 + st + c);
        float s = 0.f;
        #pragma unroll
        for (int j = 0; j < 8; ++j) {
            float v = bf2f((u16)a0[j]) + bf2f((u16)a1[j]);
            vbuf[c + j] = v;
            s += v * v;
        }
        if (c < QLORA) ssq += s;
        else if (c < QLORA + KVLORA) ssk += s;
    }
    #pragma unroll
    for (int off = 1; off < 64; off <<= 1) {
        ssq += __shfl_xor(ssq, off, 64);
        ssk += __shfl_xor(ssk, off, 64);
    }
    if ((threadIdx.x & 63) == 0) {
        r2[0][threadIdx.x >> 6] = ssq;
        r2[1][threadIdx.x >> 6] = ssk;
    }
    __syncthreads();
    float rsq = rsqrtf((r2[0][0] + r2[0][1] + r2[0][2] + r2[0][3]) / (float)QLORA + 1e-6f);
    float rsk = rsqrtf((r2[1][0] + r2[1][1] + r2[1][2] + r2[1][3]) / (float)KVLORA + 1e-6f);
    for (int c = threadIdx.x * 8; c < NCOMB; c += 2048) {
        bf16x8 o;
        if (c < QLORA) {
            #pragma unroll
            for (int j = 0; j < 8; ++j) o[j] = (short)f2bf(vbuf[c + j] * rsq * q_ln[c + j]);
            *(bf16x8*)(lqn + (size_t)row * QLORA + c) = o;
        } else if (c < QLORA + KVLORA) {
            int cc = c - QLORA;
            #pragma unroll
            for (int j = 0; j < 8; ++j) o[j] = (short)f2bf(vbuf[c + j] * rsk * kv_ln[cc + j]);
            *(bf16x8*)(kvn + (size_t)row * KVLORA + cc) = o;
        } else if (c < QLORA + KVLORA + ROPE_D) {
            int cc = c - QLORA - KVLORA;
            #pragma unroll
            for (int j = 0; j < 8; ++j) o[j] = (short)f2bf(vbuf[c + j]);
            *(bf16x8*)(kpe + (size_t)row * ROPE_D + cc) = o;
        }
    }
}

// ---------------- merged Q-prep (single bf16 slice) + K/V-prep --------------
__global__ __launch_bounds__(256)
void prep_qkv_frag(const u16* __restrict__ qh, const u16* __restrict__ kvb,
                   const u16* __restrict__ kpe, const float* __restrict__ cosb,
                   const float* __restrict__ sinb, u16* __restrict__ qfrag,
                   u16* __restrict__ kfrag, u16* __restrict__ vfrag) {
    __shared__ u16 Vs[32][136];
    const int sblk = blockIdx.x, h = blockIdx.y;
    if (blockIdx.z == 0) {
        const float sm = SM_SCALE_C;
        #pragma unroll
        for (int c = 0; c < 3; ++c) {
            int idx = c * 256 + threadIdx.x;      // 0..767
            int kk = idx >> 6;                    // 0..11
            int lane = idx & 63;
            int s = sblk * 32 + (lane & 31);
            int d0 = kk * 16 + (lane >> 5) * 8;
            const u16* p0 = qh + (size_t)s * (NHEAD * HEAD_D) + h * HEAD_D;
            bf16x8 o;
            if (d0 < NOPE_D) {
                bf16x8 a0 = *(const bf16x8*)(p0 + d0);
                #pragma unroll
                for (int j = 0; j < 8; ++j) o[j] = (short)f2bf(bf2f((u16)a0[j]) * sm);
            } else {
                int r0 = d0 - NOPE_D;
                int rp = (r0 + 32) & 63;
                bf16x8 a0 = *(const bf16x8*)(p0 + d0);
                bf16x8 b0 = *(const bf16x8*)(p0 + NOPE_D + rp);
                float sign = (r0 < 32) ? -1.f : 1.f;
                #pragma unroll
                for (int j = 0; j < 8; ++j) {
                    float cs = cosb[s * ROPE_D + r0 + j];
                    float sn = sinb[s * ROPE_D + r0 + j];
                    o[j] = (short)f2bf((bf2f((u16)a0[j]) * cs + sign * bf2f((u16)b0[j]) * sn) * sm);
                }
            }
            *(bf16x8*)(qfrag + (((size_t)h * 64 + sblk) * 12 + kk) * 512 + lane * 8) = o;
        }
    } else {
        #pragma unroll
        for (int it = 0; it < 2; ++it) {
            int idx = it * 256 + threadIdx.x;     // 0..511
            int r = idx >> 4;                     // 0..31
            int c8 = (idx & 15) * 8;              // 0..120
            int s = sblk * 32 + r;
            *(bf16x8*)&Vs[r][c8] = *(const bf16x8*)(kvb + (size_t)s * (NHEAD * 256) + h * 256 + NOPE_D + c8);
        }
        #pragma unroll
        for (int c = 0; c < 3; ++c) {
            int idx = c * 256 + threadIdx.x;
            int kk = idx >> 6;
            int lane = idx & 63;
            int s = sblk * 32 + (lane & 31);
            int d0 = kk * 16 + (lane >> 5) * 8;
            bf16x8 o;
            if (d0 < NOPE_D) {
                o = *(const bf16x8*)(kvb + (size_t)s * (NHEAD * 256) + h * 256 + d0);
            } else {
                int r0 = d0 - NOPE_D;
                const u16* kp = kpe + (size_t)s * ROPE_D;
                bf16x8 x = *(const bf16x8*)(kp + r0);
                bf16x8 rv = *(const bf16x8*)(kp + ((r0 + 32) & 63));
                float sign = (r0 < 32) ? -1.f : 1.f;
                #pragma unroll
                for (int j = 0; j < 8; ++j) {
                    float cs = cosb[s * ROPE_D + r0 + j];
                    float sn = sinb[s * ROPE_D + r0 + j];
                    o[j] = (short)f2bf(bf2f((u16)x[j]) * cs + sign * bf2f((u16)rv[j]) * sn);
                }
            }
            *(bf16x8*)(kfrag + (((size_t)h * 64 + sblk) * 12 + kk) * 512 + lane * 8) = o;
        }
        __syncthreads();
        #pragma unroll
        for (int it = 0; it < 2; ++it) {
            int idx = it * 256 + threadIdx.x;     // 0..511
            int fi = idx >> 6;                    // 0..7
            int lane = idx & 63;
            int bb = fi >> 1, h16 = fi & 1;
            int col = bb * 32 + (lane & 31);
            int row0 = h16 * 16 + (lane >> 5) * 8;
            bf16x8 o;
            #pragma unroll
            for (int j = 0; j < 8; ++j) o[j] = (short)Vs[row0 + j][col];
            *(bf16x8*)(vfrag + (((size_t)h * 64 + sblk) * 8 + fi) * 512 + lane * 8) = o;
        }
    }
}

// ---------------- split-K(2) bf16-partial reduce for the final output (f32) ----------
__global__ void reduce_out(const u16* __restrict__ P, float* __restrict__ out, int n) {
    int i = (blockIdx.x * blockDim.x + threadIdx.x) * 8;
    if (i >= n) return;
    bf16x8 a0 = *(const bf16x8*)(P + i);
    bf16x8 a1 = *(const bf16x8*)(P + (size_t)n + i);
    f32x4 o0, o1;
    #pragma unroll
    for (int j = 0; j < 4; ++j) {
        o0[j] = bf2f((u16)a0[j]) + bf2f((u16)a1[j]);
        o1[j] = bf2f((u16)a0[j + 4]) + bf2f((u16)a1[j + 4]);
    }
    *(f32x4*)(out + i) = o0;
    *(f32x4*)(out + i + 4) = o1;
}

// ---------------- flash v7: K AND V register prefetch, 4-way kv-split ----------
__global__ __launch_bounds__(256, 2)
void flash_attn4(const u16* __restrict__ qfrag, const u16* __restrict__ kfrag,
                 const u16* __restrict__ vfrag, u16* __restrict__ attn) {
    __shared__ float OB[3][128][32];   // partial O of waves 1..3
    __shared__ float MB[3][2][32];     // m,l of waves 1..3

    const int tid = threadIdx.x, lane = tid & 63, wq = tid >> 6;
    const int b = blockIdx.x;
    const int t = 63 - (b >> 4);                    // q-tile, heavy first
    const int h = ((b & 7) << 1) | ((b >> 3) & 1);  // 2 heads per XCD
    const int q0 = t * 32;
    const int lq = lane & 31;
    const int hi = lane >> 5;

    const int n = t + 1;                            // causal kv-subtiles
    const int s_lo = (wq * n) >> 2;
    const int s_hi = ((wq + 1) * n) >> 2;

    bf16x8 qfr[12];
    {
        const u16* qb = qfrag + (((size_t)h * 64 + t) * 12) * 512 + lane * 8;
        #pragma unroll
        for (int kk = 0; kk < 12; ++kk) qfr[kk] = *(const bf16x8*)(qb + kk * 512);
    }

    const u16* kfb = kfrag + ((size_t)h * 64 * 12) * 512 + lane * 8;
    const u16* vfb = vfrag + ((size_t)h * 64 * 8) * 512 + lane * 8;

    f32x16 oa[4] = {};
    float mrun = -3.0e38f, lrun = 0.f;

    bf16x8 kcur[12], vcur[8];
    {
        int psub = (s_lo < s_hi) ? s_lo : 0;
        const u16* kp = kfb + (size_t)psub * 12 * 512;
        #pragma unroll
        for (int kk = 0; kk < 12; ++kk)
            kcur[kk] = *(const bf16x8*)(kp + kk * 512);
        const u16* vp = vfb + (size_t)psub * 8 * 512;
        #pragma unroll
        for (int fi = 0; fi < 8; ++fi)
            vcur[fi] = *(const bf16x8*)(vp + fi * 512);
    }

    for (int sub = s_lo; sub < s_hi; ++sub) {
        f32x16 s0 = {}, s1 = {};
        __builtin_amdgcn_s_setprio(1);
        #pragma unroll
        for (int kk = 0; kk < 12; kk += 2) {
            s0 = __builtin_amdgcn_mfma_f32_32x32x16_bf16(kcur[kk], qfr[kk], s0, 0, 0, 0);
            s1 = __builtin_amdgcn_mfma_f32_32x32x16_bf16(kcur[kk + 1], qfr[kk + 1], s1, 0, 0, 0);
        }
        __builtin_amdgcn_s_setprio(0);
        {
            int nsub = (sub + 1 < s_hi) ? sub + 1 : sub;
            const u16* kp = kfb + (size_t)nsub * 12 * 512;
            #pragma unroll
            for (int kk = 0; kk < 12; ++kk)
                kcur[kk] = *(const bf16x8*)(kp + kk * 512);
        }
        f32x16 sv = s0 + s1;
        if (sub == t) {   // diagonal mask
            #pragma unroll
            for (int r = 0; r < 16; ++r) {
                int krow = (r & 3) + 8 * (r >> 2) + 4 * hi;
                if (krow > lq) sv[r] = -3.0e38f;
            }
        }
        float tm = sv[0];
        #pragma unroll
        for (int r = 1; r < 16; ++r) tm = fmaxf(tm, sv[r]);
        tm = fmaxf(tm, __shfl_xor(tm, 32, 64));
        if (!__all(tm - mrun <= 8.f)) {
            float mn = fmaxf(mrun, tm);
            float scl = exp2f((mrun - mn) * LOG2E);
            mrun = mn;
            lrun *= scl;
            #pragma unroll
            for (int bb = 0; bb < 4; ++bb)
                #pragma unroll
                for (int r = 0; r < 16; ++r) oa[bb][r] *= scl;
        }
        float p[16];
        float psum = 0.f;
        #pragma unroll
        for (int r = 0; r < 16; ++r) {
            p[r] = exp2f((sv[r] - mrun) * LOG2E);
            psum += p[r];
        }
        psum += __shfl_xor(psum, 32, 64);
        lrun += psum;
        u32 pw[8], sw[8];
        #pragma unroll
        for (int i = 0; i < 8; ++i)
            pw[i] = pack2bf(p[2 * i], p[2 * i + 1]);
        #pragma unroll
        for (int i = 0; i < 8; ++i)
            sw[i] = (u32)__shfl_xor((int)pw[i], 32, 64);
        union { u32 w[4]; bf16x8 v; } bf0, bf1;
        bf0.w[0] = hi ? sw[2] : pw[0];
        bf0.w[1] = hi ? sw[3] : pw[1];
        bf0.w[2] = hi ? pw[2] : sw[0];
        bf0.w[3] = hi ? pw[3] : sw[1];
        bf1.w[0] = hi ? sw[6] : pw[4];
        bf1.w[1] = hi ? sw[7] : pw[5];
        bf1.w[2] = hi ? pw[6] : sw[4];
        bf1.w[3] = hi ? pw[7] : sw[5];
        __builtin_amdgcn_s_setprio(1);
        #pragma unroll
        for (int bb = 0; bb < 4; ++bb) {
            oa[bb] = __builtin_amdgcn_mfma_f32_32x32x16_bf16(vcur[bb * 2],     bf0.v, oa[bb], 0, 0, 0);
            oa[bb] = __builtin_amdgcn_mfma_f32_32x32x16_bf16(vcur[bb * 2 + 1], bf1.v, oa[bb], 0, 0, 0);
        }
        __builtin_amdgcn_s_setprio(0);
        {
            int nsub = (sub + 1 < s_hi) ? sub + 1 : sub;
            const u16* vp = vfb + (size_t)nsub * 8 * 512;
            #pragma unroll
            for (int fi = 0; fi < 8; ++fi)
                vcur[fi] = *(const bf16x8*)(vp + fi * 512);
        }
    }

    // ---- 4-way flash-decoding merge ----
    if (wq) {
        #pragma unroll
        for (int bb = 0; bb < 4; ++bb)
            #pragma unroll
            for (int r = 0; r < 16; ++r) {
                int dv = bb * 32 + (r & 3) + 8 * (r >> 2) + 4 * hi;
                OB[wq - 1][dv][lq] = oa[bb][r];
            }
        if (lane < 32) {
            MB[wq - 1][0][lane] = mrun;
            MB[wq - 1][1][lane] = lrun;
        }
    }
    __syncthreads();
    if (!wq) {
        float m1 = MB[0][0][lq], l1 = MB[0][1][lq];
        float m2 = MB[1][0][lq], l2 = MB[1][1][lq];
        float m3 = MB[2][0][lq], l3 = MB[2][1][lq];
        float M = fmaxf(fmaxf(mrun, m1), fmaxf(m2, m3));
        float e0 = exp2f((mrun - M) * LOG2E);
        float e1 = exp2f((m1 - M) * LOG2E);
        float e2 = exp2f((m2 - M) * LOG2E);
        float e3 = exp2f((m3 - M) * LOG2E);
        float L = lrun * e0 + l1 * e1 + l2 * e2 + l3 * e3;
        float inv = 1.0f / L;
        u16* ob = attn + (size_t)(q0 + lq) * (NHEAD * V_D) + h * V_D;
        #pragma unroll
        for (int bb = 0; bb < 4; ++bb)
            #pragma unroll
            for (int rq = 0; rq < 4; ++rq) {
                u16x4 pk;
                #pragma unroll
                for (int rb = 0; rb < 4; ++rb) {
                    int r = rq * 4 + rb;
                    int dv = bb * 32 + rb + 8 * rq + 4 * hi;
                    float o = (oa[bb][r] * e0 + OB[0][dv][lq] * e1 +
                               OB[1][dv][lq] * e2 + OB[2][dv][lq] * e3) * inv;
                    pk[rb] = f2bf(o);
                }
                *(u16x4*)(ob + bb * 32 + 8 * rq + 4 * hi) = pk;
            }
    }
}

extern "C" void kernel_launch(void* const* d_in, const int* in_sizes, int n_in,
                              void* d_out, int out_size, void* d_ws, size_t ws_size,
                              hipStream_t stream) {
    const float* hs    = (const float*)d_in[0];
    const float* wq_a  = (const float*)d_in[1];
    const float* sq_a  = (const float*)d_in[2];
    const float* wq_b  = (const float*)d_in[3];
    const float* sq_b  = (const float*)d_in[4];
    const float* wkv_a = (const float*)d_in[5];
    const float* skv_a = (const float*)d_in[6];
    const float* wkv_b = (const float*)d_in[7];
    const float* skv_b = (const float*)d_in[8];
    const float* wo    = (const float*)d_in[9];
    const float* so    = (const float*)d_in[10];
    const float* q_ln  = (const float*)d_in[11];
    const float* kv_ln = (const float*)d_in[12];
    const float* cosb  = (const float*)d_in[13];
    const float* sinb  = (const float*)d_in[14];
    float* out = (float*)d_out;

    char* ws = (char*)d_ws;
    size_t off = 0;
    auto alloc = [&](size_t bytes) -> void* {
        void* p = ws + off; off += (bytes + 255) & ~(size_t)255; return p;
    };
    u16* hs_bf  = (u16*)alloc((size_t)S_LEN * HIDDEN * 2);
    u16* lqn    = (u16*)alloc((size_t)S_LEN * QLORA * 2);
    u16* kvn    = (u16*)alloc((size_t)S_LEN * KVLORA * 2);
    u16* kpe    = (u16*)alloc((size_t)S_LEN * ROPE_D * 2);
    u16* kvb    = (u16*)alloc((size_t)S_LEN * NHEAD * 256 * 2);
    u16* attn   = (u16*)alloc((size_t)S_LEN * NHEAD * V_D * 2);
    u16* qfrag  = (u16*)alloc((size_t)NHEAD * 64 * 12 * 512 * 2);
    u16* kfrag  = (u16*)alloc((size_t)NHEAD * 64 * 12 * 512 * 2);
    u16* vfrag  = (u16*)alloc((size_t)NHEAD * 64 * 8 * 512 * 2);
    u16* wcomb  = (u16*)alloc((size_t)NCOMB * HIDDEN * 2);
    u16* wqb_bf  = (u16*)alloc((size_t)(NHEAD * HEAD_D) * QLORA * 2);
    u16* wkvb_bf = (u16*)alloc((size_t)(NHEAD * 256) * KVLORA * 2);
    u16* wo_bf   = (u16*)alloc((size_t)HIDDEN * (NHEAD * V_D) * 2);
    u16* arena  = (u16*)alloc((size_t)2 * S_LEN * NCOMB * 2);   // 17.9 MB (comb z=2 is max)

    prep_weights<<<3344, 256, 0, stream>>>(
        hs, wq_a, sq_a, wq_b, sq_b, wkv_a, skv_a, wkv_b, skv_b, wo, so,
        hs_bf, wcomb, wqb_bf, wkvb_bf, wo_bf);

    // comb = hs @ [wq_a; wkv_a]^T, split-K=2 -> bf16 partials (17.9MB)
    gemm_bf16<<<dim3(NCOMB / 128, S_LEN / 128, 2), 256, 0, stream>>>(hs_bf, wcomb, arena,
        S_LEN, NCOMB, HIDDEN, HIDDEN / 2);
    reduce_rms_comb<<<S_LEN, 256, 0, stream>>>(arena, q_ln, kv_ln, lqn, kvn, kpe);

    // qh (z=1, direct bf16, 12.6MB) + kvb (direct), one merged launch: 896 blocks
    gemm_qh_kvb<<<24 * 16 + 32 * 16, 256, 0, stream>>>(lqn, wqb_bf, arena, kvn, wkvb_bf, kvb);

    // q-prep (single slice) + k/v-prep, one merged launch
    prep_qkv_frag<<<dim3(64, NHEAD, 2), 256, 0, stream>>>(arena, kvb, kpe, cosb, sinb,
        qfrag, kfrag, vfrag);

    flash_attn4<<<1024, 256, 0, stream>>>(qfrag, kfrag, vfrag, attn);

    // out = attn @ wo^T (z=2, bf16 partials, 16.8MB) -> f32 reduce
    gemm_bf16<<<dim3(16, 16, 2), 256, 0, stream>>>(attn, wo_bf, arena,
        S_LEN, HIDDEN, NHEAD * V_D, (NHEAD * V_D) / 2);
    reduce_out<<<S_LEN * HIDDEN / 8 / 256, 256, 0, stream>>>(arena, out, S_LEN * HIDDEN);
}

// Round 19
// 193.424 us; speedup vs baseline: 1.0401x; 1.0401x over previous
//
#include <hip/hip_runtime.h>
#include <hip/hip_bf16.h>

typedef unsigned short u16;
typedef unsigned int u32;
typedef __attribute__((ext_vector_type(8))) short bf16x8;
typedef __attribute__((ext_vector_type(4))) float f32x4;
typedef __attribute__((ext_vector_type(16))) float f32x16;
typedef __attribute__((ext_vector_type(4))) unsigned short u16x4;

#define S_LEN 2048
#define HIDDEN 2048
#define NHEAD 16
#define QLORA 1536
#define KVLORA 512
#define NOPE_D 128
#define ROPE_D 64
#define V_D 128
#define HEAD_D 192
#define NCOMB 2176   // QLORA + KVLORA + ROPE_D + 64 pad (N=17*128)
#define LOG2E 1.442695041f

// SOFTMAX_SCALE = 192^-0.5 * mscale^2, mscale = 0.1*ln(40)+1
__device__ __constant__ float SM_SCALE_C = (float)(0.07216878364870323 *
    ((0.1 * 3.6888794541139363 + 1.0) * (0.1 * 3.6888794541139363 + 1.0)));

__device__ inline u16 f2bf(float f) {
    __hip_bfloat16 h = __float2bfloat16(f);
    return *reinterpret_cast<u16*>(&h);
}
__device__ inline u32 pack2bf(float lo, float hi) {
    float2 v = make_float2(lo, hi);
    __hip_bfloat162 h2 = __float22bfloat162_rn(v); // v_cvt_pk_bf16_f32
    return *reinterpret_cast<u32*>(&h2);
}
__device__ inline float bf2f(u16 b) {
    union { unsigned int u; float f; } v; v.u = ((unsigned int)b) << 16;
    return v.f;
}
__device__ inline void gload_lds16(const u16* g, u16* l) {
    __builtin_amdgcn_global_load_lds(
        (const __attribute__((address_space(1))) void*)g,
        (__attribute__((address_space(3))) void*)l, 16, 0, 0);
}

// bijective XCD swizzle (m204)
__device__ __forceinline__ int xcd_swizzle(int orig, int nwg) {
    int qq = nwg >> 3, rr = nwg & 7, xcd = orig & 7, loc = orig >> 3;
    return (xcd < rr) ? (xcd * (qq + 1) + loc)
                      : (rr * (qq + 1) + (xcd - rr) * qq + loc);
}

// ---------------- weight prep: hs cvt + all 5 dequants, no LDS, one launch ----------
__global__ __launch_bounds__(256)
void prep_weights(const float* __restrict__ hs,
                  const float* __restrict__ wq_a, const float* __restrict__ sq_a,
                  const float* __restrict__ wq_b, const float* __restrict__ sq_b,
                  const float* __restrict__ wkv_a, const float* __restrict__ skv_a,
                  const float* __restrict__ wkv_b, const float* __restrict__ skv_b,
                  const float* __restrict__ wo, const float* __restrict__ so,
                  u16* __restrict__ hs_bf, u16* __restrict__ wcomb,
                  u16* __restrict__ wqb_bf, u16* __restrict__ wkvb_bf,
                  u16* __restrict__ wo_bf) {
    int r = blockIdx.x * 4 + (threadIdx.x >> 6);
    const float* W; const float* Sc; u16* out; int n, K, sc_cols;
    if (r < 2048)       { W = hs;    Sc = 0;      out = hs_bf;   n = r;        K = 2048; sc_cols = 0; }
    else if (r < 3584)  { W = wq_a;  Sc = sq_a;   out = wcomb;   n = r - 2048; K = 2048; sc_cols = 16; }
    else if (r < 4160)  { W = wkv_a; Sc = skv_a;  out = wcomb + (size_t)QLORA * 2048; n = r - 3584; K = 2048; sc_cols = 16; }
    else if (r < 7232)  { W = wq_b;  Sc = sq_b;   out = wqb_bf;  n = r - 4160; K = 1536; sc_cols = 12; }
    else if (r < 11328) { W = wkv_b; Sc = skv_b;  out = wkvb_bf; n = r - 7232; K = 512;  sc_cols = 4; }
    else                { W = wo;    Sc = so;     out = wo_bf;   n = r - 11328; K = 2048; sc_cols = 16; }
    for (int k = (threadIdx.x & 63) * 8; k < K; k += 512) {
        float sc = Sc ? Sc[(n >> 7) * sc_cols + (k >> 7)] : 1.0f;
        f32x4 v0 = *(const f32x4*)(W + (size_t)n * K + k);
        f32x4 v1 = *(const f32x4*)(W + (size_t)n * K + k + 4);
        u32 w[4];
        w[0] = pack2bf(v0[0] * sc, v0[1] * sc);
        w[1] = pack2bf(v0[2] * sc, v0[3] * sc);
        w[2] = pack2bf(v1[0] * sc, v1[1] * sc);
        w[3] = pack2bf(v1[2] * sc, v1[3] * sc);
        *(__attribute__((ext_vector_type(4))) u32*)(out + (size_t)n * K + k) =
            *( __attribute__((ext_vector_type(4))) u32*)w;
    }
}

// ---------------- GEMM core v4: BK=64 dbuf + counted vmcnt (T4), raw s_barrier -------
__device__ __forceinline__ void gemm_core(
    const u16* __restrict__ A, const u16* __restrict__ W, u16* __restrict__ C,
    int M, int N, int Ktot, int Ksub, int bm, int bn, int bz,
    u16 (*As)[128 * 64], u16 (*Ws)[128 * 64]) {
    const int tid = threadIdx.x;
    const int lane = tid & 63;
    const int wv = tid >> 6;
    const int wm = wv >> 1, wn = wv & 1;
    const int lr = lane & 15, lk = lane >> 4;
    const int srow = lane >> 3;
    const int schunk = lane & 7;

    f32x4 acc[4][4] = {};

    const int kbeg = bz * Ksub;
    const int nst = Ksub >> 6;

    auto stage = [&](int buf, int k0) {
        #pragma unroll
        for (int i = 0; i < 4; ++i) {
            int t = (wv * 4 + i) * 8 + srow;
            int cs = (schunk ^ (t & 7)) << 3;
            gload_lds16(A + (size_t)(bm + t) * Ktot + k0 + cs, &As[buf][(wv * 4 + i) * 512]);
            gload_lds16(W + (size_t)(bn + t) * Ktot + k0 + cs, &Ws[buf][(wv * 4 + i) * 512]);
        }
    };

    stage(0, kbeg);
    int cur = 0;
    for (int t = 0; t < nst; ++t) {
        if (t + 1 < nst) {
            stage(cur ^ 1, kbeg + (t + 1) * 64);            // 8 loads in flight across barriers
            asm volatile("s_waitcnt vmcnt(8)" ::: "memory"); // drain ONLY stage(cur)
        } else {
            asm volatile("s_waitcnt vmcnt(0)" ::: "memory");
        }
        __builtin_amdgcn_sched_barrier(0);                   // rule #18: pin reads below
        __builtin_amdgcn_s_barrier();                        // all waves' stage(cur) landed
        #pragma unroll
        for (int kh = 0; kh < 2; ++kh) {
            bf16x8 af[4], bfr[4];
            #pragma unroll
            for (int mi = 0; mi < 4; ++mi) {
                int r = wm * 64 + mi * 16 + lr;
                af[mi] = *(const bf16x8*)&As[cur][r * 64 + (((kh * 4 + lk) ^ (lr & 7)) << 3)];
            }
            #pragma unroll
            for (int ni = 0; ni < 4; ++ni) {
                int r = wn * 64 + ni * 16 + lr;
                bfr[ni] = *(const bf16x8*)&Ws[cur][r * 64 + (((kh * 4 + lk) ^ (lr & 7)) << 3)];
            }
            __builtin_amdgcn_s_setprio(1);
            #pragma unroll
            for (int mi = 0; mi < 4; ++mi)
                #pragma unroll
                for (int ni = 0; ni < 4; ++ni)
                    acc[mi][ni] = __builtin_amdgcn_mfma_f32_16x16x32_bf16(af[mi], bfr[ni], acc[mi][ni], 0, 0, 0);
            __builtin_amdgcn_s_setprio(0);
        }
        __builtin_amdgcn_s_barrier();                        // all reads of cur done before overwrite
        cur ^= 1;
    }

    u16* Pb = C + (size_t)bz * M * N;
    #pragma unroll
    for (int mi = 0; mi < 4; ++mi)
        #pragma unroll
        for (int ni = 0; ni < 4; ++ni)
            #pragma unroll
            for (int j = 0; j < 4; ++j) {
                int r = bm + wm * 64 + mi * 16 + lk * 4 + j;
                int c = bn + wn * 64 + ni * 16 + lr;
                if (c < N) Pb[(size_t)r * N + c] = f2bf(acc[mi][ni][j]);
            }
}

// ---------------- generic split-K GEMM (bf16 partial slices) ----------------
__global__ __launch_bounds__(256)
void gemm_bf16(const u16* __restrict__ A, const u16* __restrict__ W,
               u16* __restrict__ C, int M, int N, int Ktot, int Ksub) {
    __shared__ u16 As[2][128 * 64];
    __shared__ u16 Ws[2][128 * 64];
    const int gx = gridDim.x, gy = gridDim.y;
    const int nwg = gx * gy * gridDim.z;
    const int orig = blockIdx.x + gx * (blockIdx.y + gy * blockIdx.z);
    const int wg = xcd_swizzle(orig, nwg);
    const int bn = (wg % gx) * 128;
    const int bm = ((wg / gx) % gy) * 128;
    const int bz = wg / (gx * gy);
    gemm_core(A, W, C, M, N, Ktot, Ksub, bm, bn, bz, As, Ws);
}

// ---------------- merged qh (split-K=2) + kvb GEMM ----------------
__global__ __launch_bounds__(256)
void gemm_qh_kvb(const u16* __restrict__ lqn, const u16* __restrict__ wqb, u16* __restrict__ arena,
                 const u16* __restrict__ kvn, const u16* __restrict__ wkvb, u16* __restrict__ kvb) {
    __shared__ u16 As[2][128 * 64];
    __shared__ u16 Ws[2][128 * 64];
    const int NWG = 24 * 16 * 2 + 32 * 16;   // 1280
    const int wg = xcd_swizzle(blockIdx.x, NWG);
    if (wg < 24 * 16 * 2) {
        const int bn = (wg % 24) * 128;
        const int bm = ((wg / 24) % 16) * 128;
        const int bz = wg / (24 * 16);
        gemm_core(lqn, wqb, arena, S_LEN, NHEAD * HEAD_D, QLORA, 768, bm, bn, bz, As, Ws);
    } else {
        const int w2 = wg - 24 * 16 * 2;
        const int bn = (w2 % 32) * 128;
        const int bm = (w2 / 32) * 128;
        gemm_core(kvn, wkvb, kvb, S_LEN, NHEAD * 256, KVLORA, 512, bm, bn, 0, As, Ws);
    }
}

// ---------------- fused split-K(2) bf16-partial reduce + dual rmsnorm ----------------
__global__ __launch_bounds__(256)
void reduce_rms_comb(const u16* __restrict__ P,
                     const float* __restrict__ q_ln, const float* __restrict__ kv_ln,
                     u16* __restrict__ lqn, u16* __restrict__ kvn, u16* __restrict__ kpe) {
    __shared__ float vbuf[NCOMB];
    __shared__ float r2[2][4];
    const int row = blockIdx.x;
    const u16* p0 = P + (size_t)row * NCOMB;
    const size_t st = (size_t)S_LEN * NCOMB;
    float ssq = 0.f, ssk = 0.f;
    for (int c = threadIdx.x * 8; c < NCOMB; c += 2048) {
        bf16x8 a0 = *(const bf16x8*)(p0 + c);
        bf16x8 a1 = *(const bf16x8*)(p0 + st + c);
        float s = 0.f;
        #pragma unroll
        for (int j = 0; j < 8; ++j) {
            float v = bf2f((u16)a0[j]) + bf2f((u16)a1[j]);
            vbuf[c + j] = v;
            s += v * v;
        }
        if (c < QLORA) ssq += s;
        else if (c < QLORA + KVLORA) ssk += s;
    }
    #pragma unroll
    for (int off = 1; off < 64; off <<= 1) {
        ssq += __shfl_xor(ssq, off, 64);
        ssk += __shfl_xor(ssk, off, 64);
    }
    if ((threadIdx.x & 63) == 0) {
        r2[0][threadIdx.x >> 6] = ssq;
        r2[1][threadIdx.x >> 6] = ssk;
    }
    __syncthreads();
    float rsq = rsqrtf((r2[0][0] + r2[0][1] + r2[0][2] + r2[0][3]) / (float)QLORA + 1e-6f);
    float rsk = rsqrtf((r2[1][0] + r2[1][1] + r2[1][2] + r2[1][3]) / (float)KVLORA + 1e-6f);
    for (int c = threadIdx.x * 8; c < NCOMB; c += 2048) {
        bf16x8 o;
        if (c < QLORA) {
            #pragma unroll
            for (int j = 0; j < 8; ++j) o[j] = (short)f2bf(vbuf[c + j] * rsq * q_ln[c + j]);
            *(bf16x8*)(lqn + (size_t)row * QLORA + c) = o;
        } else if (c < QLORA + KVLORA) {
            int cc = c - QLORA;
            #pragma unroll
            for (int j = 0; j < 8; ++j) o[j] = (short)f2bf(vbuf[c + j] * rsk * kv_ln[cc + j]);
            *(bf16x8*)(kvn + (size_t)row * KVLORA + cc) = o;
        } else if (c < QLORA + KVLORA + ROPE_D) {
            int cc = c - QLORA - KVLORA;
            #pragma unroll
            for (int j = 0; j < 8; ++j) o[j] = (short)f2bf(vbuf[c + j]);
            *(bf16x8*)(kpe + (size_t)row * ROPE_D + cc) = o;
        }
    }
}

// ---------------- merged Q-prep (from 2 bf16 partial slices) + K/V-prep --------------
__global__ __launch_bounds__(256)
void prep_qkv_frag(const u16* __restrict__ P, const u16* __restrict__ kvb,
                   const u16* __restrict__ kpe, const float* __restrict__ cosb,
                   const float* __restrict__ sinb, u16* __restrict__ qfrag,
                   u16* __restrict__ kfrag, u16* __restrict__ vfrag) {
    __shared__ u16 Vs[32][136];
    const int sblk = blockIdx.x, h = blockIdx.y;
    if (blockIdx.z == 0) {
        const float sm = SM_SCALE_C;
        const size_t st = (size_t)S_LEN * (NHEAD * HEAD_D);
        #pragma unroll
        for (int c = 0; c < 3; ++c) {
            int idx = c * 256 + threadIdx.x;      // 0..767
            int kk = idx >> 6;                    // 0..11
            int lane = idx & 63;
            int s = sblk * 32 + (lane & 31);
            int d0 = kk * 16 + (lane >> 5) * 8;
            const u16* p0 = P + (size_t)s * (NHEAD * HEAD_D) + h * HEAD_D;
            float x[8];
            {
                bf16x8 a0 = *(const bf16x8*)(p0 + d0);
                bf16x8 a1 = *(const bf16x8*)(p0 + st + d0);
                #pragma unroll
                for (int j = 0; j < 8; ++j)
                    x[j] = bf2f((u16)a0[j]) + bf2f((u16)a1[j]);
            }
            bf16x8 o;
            if (d0 < NOPE_D) {
                #pragma unroll
                for (int j = 0; j < 8; ++j) o[j] = (short)f2bf(x[j] * sm);
            } else {
                int r0 = d0 - NOPE_D;
                int rp = (r0 + 32) & 63;
                float rv[8];
                bf16x8 b0 = *(const bf16x8*)(p0 + NOPE_D + rp);
                bf16x8 b1 = *(const bf16x8*)(p0 + st + NOPE_D + rp);
                #pragma unroll
                for (int j = 0; j < 8; ++j)
                    rv[j] = bf2f((u16)b0[j]) + bf2f((u16)b1[j]);
                float sign = (r0 < 32) ? -1.f : 1.f;
                #pragma unroll
                for (int j = 0; j < 8; ++j) {
                    float cs = cosb[s * ROPE_D + r0 + j];
                    float sn = sinb[s * ROPE_D + r0 + j];
                    o[j] = (short)f2bf((x[j] * cs + sign * rv[j] * sn) * sm);
                }
            }
            *(bf16x8*)(qfrag + (((size_t)h * 64 + sblk) * 12 + kk) * 512 + lane * 8) = o;
        }
    } else {
        #pragma unroll
        for (int it = 0; it < 2; ++it) {
            int idx = it * 256 + threadIdx.x;     // 0..511
            int r = idx >> 4;                     // 0..31
            int c8 = (idx & 15) * 8;              // 0..120
            int s = sblk * 32 + r;
            *(bf16x8*)&Vs[r][c8] = *(const bf16x8*)(kvb + (size_t)s * (NHEAD * 256) + h * 256 + NOPE_D + c8);
        }
        #pragma unroll
        for (int c = 0; c < 3; ++c) {
            int idx = c * 256 + threadIdx.x;
            int kk = idx >> 6;
            int lane = idx & 63;
            int s = sblk * 32 + (lane & 31);
            int d0 = kk * 16 + (lane >> 5) * 8;
            bf16x8 o;
            if (d0 < NOPE_D) {
                o = *(const bf16x8*)(kvb + (size_t)s * (NHEAD * 256) + h * 256 + d0);
            } else {
                int r0 = d0 - NOPE_D;
                const u16* kp = kpe + (size_t)s * ROPE_D;
                bf16x8 x = *(const bf16x8*)(kp + r0);
                bf16x8 rv = *(const bf16x8*)(kp + ((r0 + 32) & 63));
                float sign = (r0 < 32) ? -1.f : 1.f;
                #pragma unroll
                for (int j = 0; j < 8; ++j) {
                    float cs = cosb[s * ROPE_D + r0 + j];
                    float sn = sinb[s * ROPE_D + r0 + j];
                    o[j] = (short)f2bf(bf2f((u16)x[j]) * cs + sign * bf2f((u16)rv[j]) * sn);
                }
            }
            *(bf16x8*)(kfrag + (((size_t)h * 64 + sblk) * 12 + kk) * 512 + lane * 8) = o;
        }
        __syncthreads();
        #pragma unroll
        for (int it = 0; it < 2; ++it) {
            int idx = it * 256 + threadIdx.x;     // 0..511
            int fi = idx >> 6;                    // 0..7
            int lane = idx & 63;
            int bb = fi >> 1, h16 = fi & 1;
            int col = bb * 32 + (lane & 31);
            int row0 = h16 * 16 + (lane >> 5) * 8;
            bf16x8 o;
            #pragma unroll
            for (int j = 0; j < 8; ++j) o[j] = (short)Vs[row0 + j][col];
            *(bf16x8*)(vfrag + (((size_t)h * 64 + sblk) * 8 + fi) * 512 + lane * 8) = o;
        }
    }
}

// ---------------- split-K(2) bf16-partial reduce for the final output (f32) ----------
__global__ void reduce_out(const u16* __restrict__ P, float* __restrict__ out, int n) {
    int i = (blockIdx.x * blockDim.x + threadIdx.x) * 8;
    if (i >= n) return;
    bf16x8 a0 = *(const bf16x8*)(P + i);
    bf16x8 a1 = *(const bf16x8*)(P + (size_t)n + i);
    f32x4 o0, o1;
    #pragma unroll
    for (int j = 0; j < 4; ++j) {
        o0[j] = bf2f((u16)a0[j]) + bf2f((u16)a1[j]);
        o1[j] = bf2f((u16)a0[j + 4]) + bf2f((u16)a1[j + 4]);
    }
    *(f32x4*)(out + i) = o0;
    *(f32x4*)(out + i + 4) = o1;
}

// ---------------- flash v7: K AND V register prefetch, 4-way kv-split ----------
__global__ __launch_bounds__(256, 2)
void flash_attn4(const u16* __restrict__ qfrag, const u16* __restrict__ kfrag,
                 const u16* __restrict__ vfrag, u16* __restrict__ attn) {
    __shared__ float OB[3][128][32];   // partial O of waves 1..3
    __shared__ float MB[3][2][32];     // m,l of waves 1..3

    const int tid = threadIdx.x, lane = tid & 63, wq = tid >> 6;
    const int b = blockIdx.x;
    const int t = 63 - (b >> 4);                    // q-tile, heavy first
    const int h = ((b & 7) << 1) | ((b >> 3) & 1);  // 2 heads per XCD
    const int q0 = t * 32;
    const int lq = lane & 31;
    const int hi = lane >> 5;

    const int n = t + 1;                            // causal kv-subtiles
    const int s_lo = (wq * n) >> 2;
    const int s_hi = ((wq + 1) * n) >> 2;

    bf16x8 qfr[12];
    {
        const u16* qb = qfrag + (((size_t)h * 64 + t) * 12) * 512 + lane * 8;
        #pragma unroll
        for (int kk = 0; kk < 12; ++kk) qfr[kk] = *(const bf16x8*)(qb + kk * 512);
    }

    const u16* kfb = kfrag + ((size_t)h * 64 * 12) * 512 + lane * 8;
    const u16* vfb = vfrag + ((size_t)h * 64 * 8) * 512 + lane * 8;

    f32x16 oa[4] = {};
    float mrun = -3.0e38f, lrun = 0.f;

    bf16x8 kcur[12], vcur[8];
    {
        int psub = (s_lo < s_hi) ? s_lo : 0;
        const u16* kp = kfb + (size_t)psub * 12 * 512;
        #pragma unroll
        for (int kk = 0; kk < 12; ++kk)
            kcur[kk] = *(const bf16x8*)(kp + kk * 512);
        const u16* vp = vfb + (size_t)psub * 8 * 512;
        #pragma unroll
        for (int fi = 0; fi < 8; ++fi)
            vcur[fi] = *(const bf16x8*)(vp + fi * 512);
    }

    for (int sub = s_lo; sub < s_hi; ++sub) {
        f32x16 s0 = {}, s1 = {};
        __builtin_amdgcn_s_setprio(1);
        #pragma unroll
        for (int kk = 0; kk < 12; kk += 2) {
            s0 = __builtin_amdgcn_mfma_f32_32x32x16_bf16(kcur[kk], qfr[kk], s0, 0, 0, 0);
            s1 = __builtin_amdgcn_mfma_f32_32x32x16_bf16(kcur[kk + 1], qfr[kk + 1], s1, 0, 0, 0);
        }
        __builtin_amdgcn_s_setprio(0);
        {
            int nsub = (sub + 1 < s_hi) ? sub + 1 : sub;
            const u16* kp = kfb + (size_t)nsub * 12 * 512;
            #pragma unroll
            for (int kk = 0; kk < 12; ++kk)
                kcur[kk] = *(const bf16x8*)(kp + kk * 512);
        }
        f32x16 sv = s0 + s1;
        if (sub == t) {   // diagonal mask
            #pragma unroll
            for (int r = 0; r < 16; ++r) {
                int krow = (r & 3) + 8 * (r >> 2) + 4 * hi;
                if (krow > lq) sv[r] = -3.0e38f;
            }
        }
        float tm = sv[0];
        #pragma unroll
        for (int r = 1; r < 16; ++r) tm = fmaxf(tm, sv[r]);
        tm = fmaxf(tm, __shfl_xor(tm, 32, 64));
        if (!__all(tm - mrun <= 8.f)) {
            float mn = fmaxf(mrun, tm);
            float scl = exp2f((mrun - mn) * LOG2E);
            mrun = mn;
            lrun *= scl;
            #pragma unroll
            for (int bb = 0; bb < 4; ++bb)
                #pragma unroll
                for (int r = 0; r < 16; ++r) oa[bb][r] *= scl;
        }
        float p[16];
        float psum = 0.f;
        #pragma unroll
        for (int r = 0; r < 16; ++r) {
            p[r] = exp2f((sv[r] - mrun) * LOG2E);
            psum += p[r];
        }
        psum += __shfl_xor(psum, 32, 64);
        lrun += psum;
        u32 pw[8], sw[8];
        #pragma unroll
        for (int i = 0; i < 8; ++i)
            pw[i] = pack2bf(p[2 * i], p[2 * i + 1]);
        #pragma unroll
        for (int i = 0; i < 8; ++i)
            sw[i] = (u32)__shfl_xor((int)pw[i], 32, 64);
        union { u32 w[4]; bf16x8 v; } bf0, bf1;
        bf0.w[0] = hi ? sw[2] : pw[0];
        bf0.w[1] = hi ? sw[3] : pw[1];
        bf0.w[2] = hi ? pw[2] : sw[0];
        bf0.w[3] = hi ? pw[3] : sw[1];
        bf1.w[0] = hi ? sw[6] : pw[4];
        bf1.w[1] = hi ? sw[7] : pw[5];
        bf1.w[2] = hi ? pw[6] : sw[4];
        bf1.w[3] = hi ? pw[7] : sw[5];
        __builtin_amdgcn_s_setprio(1);
        #pragma unroll
        for (int bb = 0; bb < 4; ++bb) {
            oa[bb] = __builtin_amdgcn_mfma_f32_32x32x16_bf16(vcur[bb * 2],     bf0.v, oa[bb], 0, 0, 0);
            oa[bb] = __builtin_amdgcn_mfma_f32_32x32x16_bf16(vcur[bb * 2 + 1], bf1.v, oa[bb], 0, 0, 0);
        }
        __builtin_amdgcn_s_setprio(0);
        {
            int nsub = (sub + 1 < s_hi) ? sub + 1 : sub;
            const u16* vp = vfb + (size_t)nsub * 8 * 512;
            #pragma unroll
            for (int fi = 0; fi < 8; ++fi)
                vcur[fi] = *(const bf16x8*)(vp + fi * 512);
        }
    }

    // ---- 4-way flash-decoding merge ----
    if (wq) {
        #pragma unroll
        for (int bb = 0; bb < 4; ++bb)
            #pragma unroll
            for (int r = 0; r < 16; ++r) {
                int dv = bb * 32 + (r & 3) + 8 * (r >> 2) + 4 * hi;
                OB[wq - 1][dv][lq] = oa[bb][r];
            }
        if (lane < 32) {
            MB[wq - 1][0][lane] = mrun;
            MB[wq - 1][1][lane] = lrun;
        }
    }
    __syncthreads();
    if (!wq) {
        float m1 = MB[0][0][lq], l1 = MB[0][1][lq];
        float m2 = MB[1][0][lq], l2 = MB[1][1][lq];
        float m3 = MB[2][0][lq], l3 = MB[2][1][lq];
        float M = fmaxf(fmaxf(mrun, m1), fmaxf(m2, m3));
        float e0 = exp2f((mrun - M) * LOG2E);
        float e1 = exp2f((m1 - M) * LOG2E);
        float e2 = exp2f((m2 - M) * LOG2E);
        float e3 = exp2f((m3 - M) * LOG2E);
        float L = lrun * e0 + l1 * e1 + l2 * e2 + l3 * e3;
        float inv = 1.0f / L;
        u16* ob = attn + (size_t)(q0 + lq) * (NHEAD * V_D) + h * V_D;
        #pragma unroll
        for (int bb = 0; bb < 4; ++bb)
            #pragma unroll
            for (int rq = 0; rq < 4; ++rq) {
                u16x4 pk;
                #pragma unroll
                for (int rb = 0; rb < 4; ++rb) {
                    int r = rq * 4 + rb;
                    int dv = bb * 32 + rb + 8 * rq + 4 * hi;
                    float o = (oa[bb][r] * e0 + OB[0][dv][lq] * e1 +
                               OB[1][dv][lq] * e2 + OB[2][dv][lq] * e3) * inv;
                    pk[rb] = f2bf(o);
                }
                *(u16x4*)(ob + bb * 32 + 8 * rq + 4 * hi) = pk;
            }
    }
}

extern "C" void kernel_launch(void* const* d_in, const int* in_sizes, int n_in,
                              void* d_out, int out_size, void* d_ws, size_t ws_size,
                              hipStream_t stream) {
    const float* hs    = (const float*)d_in[0];
    const float* wq_a  = (const float*)d_in[1];
    const float* sq_a  = (const float*)d_in[2];
    const float* wq_b  = (const float*)d_in[3];
    const float* sq_b  = (const float*)d_in[4];
    const float* wkv_a = (const float*)d_in[5];
    const float* skv_a = (const float*)d_in[6];
    const float* wkv_b = (const float*)d_in[7];
    const float* skv_b = (const float*)d_in[8];
    const float* wo    = (const float*)d_in[9];
    const float* so    = (const float*)d_in[10];
    const float* q_ln  = (const float*)d_in[11];
    const float* kv_ln = (const float*)d_in[12];
    const float* cosb  = (const float*)d_in[13];
    const float* sinb  = (const float*)d_in[14];
    float* out = (float*)d_out;

    char* ws = (char*)d_ws;
    size_t off = 0;
    auto alloc = [&](size_t bytes) -> void* {
        void* p = ws + off; off += (bytes + 255) & ~(size_t)255; return p;
    };
    u16* hs_bf  = (u16*)alloc((size_t)S_LEN * HIDDEN * 2);
    u16* lqn    = (u16*)alloc((size_t)S_LEN * QLORA * 2);
    u16* kvn    = (u16*)alloc((size_t)S_LEN * KVLORA * 2);
    u16* kpe    = (u16*)alloc((size_t)S_LEN * ROPE_D * 2);
    u16* kvb    = (u16*)alloc((size_t)S_LEN * NHEAD * 256 * 2);
    u16* attn   = (u16*)alloc((size_t)S_LEN * NHEAD * V_D * 2);
    u16* qfrag  = (u16*)alloc((size_t)NHEAD * 64 * 12 * 512 * 2);
    u16* kfrag  = (u16*)alloc((size_t)NHEAD * 64 * 12 * 512 * 2);
    u16* vfrag  = (u16*)alloc((size_t)NHEAD * 64 * 8 * 512 * 2);
    u16* wcomb  = (u16*)alloc((size_t)NCOMB * HIDDEN * 2);
    u16* wqb_bf  = (u16*)alloc((size_t)(NHEAD * HEAD_D) * QLORA * 2);
    u16* wkvb_bf = (u16*)alloc((size_t)(NHEAD * 256) * KVLORA * 2);
    u16* wo_bf   = (u16*)alloc((size_t)HIDDEN * (NHEAD * V_D) * 2);
    u16* arena  = (u16*)alloc((size_t)2 * S_LEN * (NHEAD * HEAD_D) * 2);   // 25.2 MB (qh z=2 is max)

    prep_weights<<<3344, 256, 0, stream>>>(
        hs, wq_a, sq_a, wq_b, sq_b, wkv_a, skv_a, wkv_b, skv_b, wo, so,
        hs_bf, wcomb, wqb_bf, wkvb_bf, wo_bf);

    // comb = hs @ [wq_a; wkv_a]^T, split-K=2 -> bf16 partials (17.9MB)
    gemm_bf16<<<dim3(NCOMB / 128, S_LEN / 128, 2), 256, 0, stream>>>(hs_bf, wcomb, arena,
        S_LEN, NCOMB, HIDDEN, HIDDEN / 2);
    reduce_rms_comb<<<S_LEN, 256, 0, stream>>>(arena, q_ln, kv_ln, lqn, kvn, kpe);

    // qh (split-K=2, bf16 partials, 25.2MB) + kvb (direct), one merged launch
    gemm_qh_kvb<<<24 * 16 * 2 + 32 * 16, 256, 0, stream>>>(lqn, wqb_bf, arena, kvn, wkvb_bf, kvb);

    // q-prep (reduces 2 slices) + k/v-prep, one merged launch
    prep_qkv_frag<<<dim3(64, NHEAD, 2), 256, 0, stream>>>(arena, kvb, kpe, cosb, sinb,
        qfrag, kfrag, vfrag);

    flash_attn4<<<1024, 256, 0, stream>>>(qfrag, kfrag, vfrag, attn);

    // out = attn @ wo^T (z=2, bf16 partials, 16.8MB) -> f32 reduce
    gemm_bf16<<<dim3(16, 16, 2), 256, 0, stream>>>(attn, wo_bf, arena,
        S_LEN, HIDDEN, NHEAD * V_D, (NHEAD * V_D) / 2);
    reduce_out<<<S_LEN * HIDDEN / 8 / 256, 256, 0, stream>>>(arena, out, S_LEN * HIDDEN);
}